// Round 1
// baseline (1523.280 us; speedup 1.0000x reference)
//
#include <hip/hip_runtime.h>

// WeightedGIN: 2 layers of {scatter-add(w * x[src] -> dst), MLP(relu(A@W1.T)@W2.T)}, then row L2-norm.
// N=50000 nodes, E=800000 edges, D=64.

#define DIM 64

// One edge handled by 16 lanes (float4 each). Gather x[src] row (256B coalesced),
// scale by w, atomicAdd into agg[dst] row.
__global__ __launch_bounds__(256) void scatter_k(const float* __restrict__ x,
                                                 const int* __restrict__ ei,
                                                 const float* __restrict__ ew,
                                                 float* __restrict__ agg,
                                                 int n_edges) {
    int t = blockIdx.x * blockDim.x + threadIdx.x;
    int e = t >> 4;      // 16 lanes per edge
    int li = t & 15;     // which float4 of the 64-float row
    if (e >= n_edges) return;
    int s = ei[e];               // src row
    int d = ei[n_edges + e];     // dst row
    float w = ew[e];
    float4 v = reinterpret_cast<const float4*>(x)[s * 16 + li];
    float* ap = agg + (size_t)d * DIM + li * 4;
    atomicAdd(ap + 0, w * v.x);
    atomicAdd(ap + 1, w * v.y);
    atomicAdd(ap + 2, w * v.z);
    atomicAdd(ap + 3, w * v.w);
}

// Thread-per-node MLP: out = relu(agg @ W1.T) @ W2.T, optional row L2-normalize.
// W1/W2 staged in LDS; all register arrays statically indexed (inner loops unrolled).
__global__ __launch_bounds__(256) void mlp_k(const float* __restrict__ agg,
                                             const float* __restrict__ W1,
                                             const float* __restrict__ W2,
                                             float* __restrict__ out,
                                             int n_nodes, int do_norm) {
    __shared__ float sW1[DIM * DIM];
    __shared__ float sW2[DIM * DIM];
    for (int i = threadIdx.x; i < (DIM * DIM) / 4; i += blockDim.x) {
        reinterpret_cast<float4*>(sW1)[i] = reinterpret_cast<const float4*>(W1)[i];
        reinterpret_cast<float4*>(sW2)[i] = reinterpret_cast<const float4*>(W2)[i];
    }
    __syncthreads();

    int node = blockIdx.x * blockDim.x + threadIdx.x;
    if (node >= n_nodes) return;

    float a[DIM];
#pragma unroll
    for (int k4 = 0; k4 < DIM / 4; ++k4) {
        float4 v = reinterpret_cast<const float4*>(agg + (size_t)node * DIM)[k4];
        a[4 * k4 + 0] = v.x; a[4 * k4 + 1] = v.y;
        a[4 * k4 + 2] = v.z; a[4 * k4 + 3] = v.w;
    }

    float o[DIM];
#pragma unroll
    for (int j = 0; j < DIM; ++j) o[j] = 0.f;

    // h_j = relu(sum_k a[k] * W1[j][k]); then rank-1 update o[j2] += h_j * W2[j2][j].
    for (int j = 0; j < DIM; ++j) {   // runtime loop; inner loops unrolled
        float h = 0.f;
#pragma unroll
        for (int k = 0; k < DIM; ++k) h = fmaf(a[k], sW1[j * DIM + k], h);
        h = fmaxf(h, 0.f);
#pragma unroll
        for (int j2 = 0; j2 < DIM; ++j2) o[j2] = fmaf(h, sW2[j2 * DIM + j], o[j2]);
    }

    float scale = 1.f;
    if (do_norm) {
        float ss = 0.f;
#pragma unroll
        for (int j = 0; j < DIM; ++j) ss = fmaf(o[j], o[j], ss);
        float nrm = sqrtf(ss);
        scale = 1.f / fmaxf(nrm, 1e-12f);
    }

#pragma unroll
    for (int j4 = 0; j4 < DIM / 4; ++j4) {
        float4 v;
        v.x = o[4 * j4 + 0] * scale; v.y = o[4 * j4 + 1] * scale;
        v.z = o[4 * j4 + 2] * scale; v.w = o[4 * j4 + 3] * scale;
        reinterpret_cast<float4*>(out + (size_t)node * DIM)[j4] = v;
    }
}

extern "C" void kernel_launch(void* const* d_in, const int* in_sizes, int n_in,
                              void* d_out, int out_size, void* d_ws, size_t ws_size,
                              hipStream_t stream) {
    const float* x    = (const float*)d_in[0];
    const int*   ei   = (const int*)d_in[1];     // [2, E] (src row, then dst row)
    const float* ew   = (const float*)d_in[2];
    const float* W1_0 = (const float*)d_in[3];
    const float* W2_0 = (const float*)d_in[4];
    const float* W1_1 = (const float*)d_in[5];
    const float* W2_1 = (const float*)d_in[6];
    float* out = (float*)d_out;

    int n_nodes = in_sizes[0] / DIM;
    int n_edges = in_sizes[2];

    float* agg = (float*)d_ws;                       // [N, 64] f32 = 12.8 MB
    size_t agg_bytes = (size_t)n_nodes * DIM * sizeof(float);

    int scat_blocks = (int)(((size_t)n_edges * 16 + 255) / 256);
    int mlp_blocks  = (n_nodes + 255) / 256;

    // ---- Layer 1 ----
    hipMemsetAsync(agg, 0, agg_bytes, stream);
    scatter_k<<<scat_blocks, 256, 0, stream>>>(x, ei, ew, agg, n_edges);
    // x1 lives in d_out (fully overwritten later by mlp2 which only reads agg)
    mlp_k<<<mlp_blocks, 256, 0, stream>>>(agg, W1_0, W2_0, out, n_nodes, 0);

    // ---- Layer 2 ----
    hipMemsetAsync(agg, 0, agg_bytes, stream);
    scatter_k<<<scat_blocks, 256, 0, stream>>>(out, ei, ew, agg, n_edges);
    mlp_k<<<mlp_blocks, 256, 0, stream>>>(agg, W1_1, W2_1, out, n_nodes, 1);
}

// Round 2
// 448.668 us; speedup vs baseline: 3.3951x; 3.3951x over previous
//
#include <hip/hip_runtime.h>

// WeightedGIN 2-layer + L2-normalize. N=50000, E=800000, D=64.
// Strategy: build dst-CSR once per call (hist + scan + reorder, ~1.6M int atomics total),
// then atomic-free wave-per-node gather for both layers. Avoids the 2x51.2M f32 atomics
// (800MB HBM write-through each) that made the scatter version 2x680us.

#define DIM 64
#define SCAN_T 1024

// ---- Pass 1: histogram of dst ----
__global__ __launch_bounds__(256) void hist_k(const int* __restrict__ ei,
                                              int* __restrict__ cnt, int n_edges) {
    int e = blockIdx.x * blockDim.x + threadIdx.x;
    if (e < n_edges) atomicAdd(&cnt[ei[n_edges + e]], 1);
}

// ---- Pass 2: exclusive prefix sum over cnt[0..n) -> offs[0..n], cursor copy ----
__global__ __launch_bounds__(SCAN_T) void scan_k(const int* __restrict__ cnt,
                                                 int* __restrict__ offs,
                                                 int* __restrict__ cursor, int n) {
    __shared__ int part[SCAN_T];
    int t = threadIdx.x;
    int chunk = (n + SCAN_T - 1) / SCAN_T;
    int b = t * chunk;
    int e = min(n, b + chunk);
    int s = 0;
    for (int i = b; i < e; ++i) s += cnt[i];
    part[t] = s;
    __syncthreads();
    for (int off = 1; off < SCAN_T; off <<= 1) {   // Hillis-Steele inclusive scan
        int v = (t >= off) ? part[t - off] : 0;
        __syncthreads();
        part[t] += v;
        __syncthreads();
    }
    int run = part[t] - s;                          // exclusive prefix of this chunk
    for (int i = b; i < e; ++i) {
        int c = cnt[i];
        offs[i] = run;
        cursor[i] = run;
        run += c;
    }
    if (t == SCAN_T - 1) offs[n] = run;             // == n_edges
}

// ---- Pass 3: scatter edges into dst-sorted payload (src_bits, w) ----
__global__ __launch_bounds__(256) void reorder_k(const int* __restrict__ ei,
                                                 const float* __restrict__ ew,
                                                 int* __restrict__ cursor,
                                                 float2* __restrict__ se, int n_edges) {
    int e = blockIdx.x * blockDim.x + threadIdx.x;
    if (e >= n_edges) return;
    int s = ei[e];
    int d = ei[n_edges + e];
    int pos = atomicAdd(&cursor[d], 1);
    se[pos] = make_float2(__int_as_float(s), ew[e]);
}

// ---- Per layer: wave-per-node gather-accumulate (atomic-free) ----
// Lane i owns feature i. Each edge step: broadcast payload + one coalesced 256B row read.
__global__ __launch_bounds__(256) void gather_k(const float* __restrict__ x,
                                                const float2* __restrict__ se,
                                                const int* __restrict__ offs,
                                                float* __restrict__ agg, int n_nodes) {
    int w = (blockIdx.x * blockDim.x + threadIdx.x) >> 6;   // wave id = node
    int lane = threadIdx.x & 63;
    if (w >= n_nodes) return;
    int beg = offs[w], end = offs[w + 1];
    float acc0 = 0.f, acc1 = 0.f;
    int e = beg;
    for (; e + 1 < end; e += 2) {                           // 2-way ILP
        float2 p0 = se[e];
        float2 p1 = se[e + 1];
        acc0 = fmaf(p0.y, x[(size_t)__float_as_int(p0.x) * DIM + lane], acc0);
        acc1 = fmaf(p1.y, x[(size_t)__float_as_int(p1.x) * DIM + lane], acc1);
    }
    if (e < end) {
        float2 p = se[e];
        acc0 = fmaf(p.y, x[(size_t)__float_as_int(p.x) * DIM + lane], acc0);
    }
    agg[(size_t)w * DIM + lane] = acc0 + acc1;
}

// ---- MLP: out = relu(agg @ W1.T) @ W2.T, optional row L2-normalize ----
// float4 LDS reads (broadcast, conflict-free) + W2 pre-transposed in LDS.
__global__ __launch_bounds__(256) void mlp_k(const float* __restrict__ agg,
                                             const float* __restrict__ W1,
                                             const float* __restrict__ W2,
                                             float* __restrict__ out,
                                             int n_nodes, int do_norm) {
    __shared__ float4 sW1[DIM * (DIM / 4)];    // [j][k4]
    __shared__ float4 sW2T[DIM * (DIM / 4)];   // [j][j2_4] = W2[j2][j] transposed
    for (int i = threadIdx.x; i < DIM * (DIM / 4); i += blockDim.x)
        sW1[i] = reinterpret_cast<const float4*>(W1)[i];
    for (int i = threadIdx.x; i < DIM * DIM; i += blockDim.x) {
        int j2 = i >> 6, j = i & 63;
        reinterpret_cast<float*>(sW2T)[j * DIM + j2] = W2[i];
    }
    __syncthreads();

    int node = blockIdx.x * blockDim.x + threadIdx.x;
    if (node >= n_nodes) return;

    float4 a[DIM / 4];
#pragma unroll
    for (int k4 = 0; k4 < DIM / 4; ++k4)
        a[k4] = reinterpret_cast<const float4*>(agg + (size_t)node * DIM)[k4];

    float4 o[DIM / 4];
#pragma unroll
    for (int j4 = 0; j4 < DIM / 4; ++j4) o[j4] = make_float4(0.f, 0.f, 0.f, 0.f);

    for (int j = 0; j < DIM; ++j) {
        float h = 0.f;
#pragma unroll
        for (int k4 = 0; k4 < DIM / 4; ++k4) {
            float4 wv = sW1[j * (DIM / 4) + k4];
            h = fmaf(a[k4].x, wv.x, h);
            h = fmaf(a[k4].y, wv.y, h);
            h = fmaf(a[k4].z, wv.z, h);
            h = fmaf(a[k4].w, wv.w, h);
        }
        h = fmaxf(h, 0.f);
#pragma unroll
        for (int j4 = 0; j4 < DIM / 4; ++j4) {
            float4 wv = sW2T[j * (DIM / 4) + j4];
            o[j4].x = fmaf(h, wv.x, o[j4].x);
            o[j4].y = fmaf(h, wv.y, o[j4].y);
            o[j4].z = fmaf(h, wv.z, o[j4].z);
            o[j4].w = fmaf(h, wv.w, o[j4].w);
        }
    }

    float scale = 1.f;
    if (do_norm) {
        float ss = 0.f;
#pragma unroll
        for (int j4 = 0; j4 < DIM / 4; ++j4) {
            ss = fmaf(o[j4].x, o[j4].x, ss);
            ss = fmaf(o[j4].y, o[j4].y, ss);
            ss = fmaf(o[j4].z, o[j4].z, ss);
            ss = fmaf(o[j4].w, o[j4].w, ss);
        }
        scale = 1.f / fmaxf(sqrtf(ss), 1e-12f);
    }

#pragma unroll
    for (int j4 = 0; j4 < DIM / 4; ++j4) {
        float4 v = o[j4];
        v.x *= scale; v.y *= scale; v.z *= scale; v.w *= scale;
        reinterpret_cast<float4*>(out + (size_t)node * DIM)[j4] = v;
    }
}

extern "C" void kernel_launch(void* const* d_in, const int* in_sizes, int n_in,
                              void* d_out, int out_size, void* d_ws, size_t ws_size,
                              hipStream_t stream) {
    const float* x    = (const float*)d_in[0];
    const int*   ei   = (const int*)d_in[1];     // [2,E]: src row then dst row
    const float* ew   = (const float*)d_in[2];
    const float* W1_0 = (const float*)d_in[3];
    const float* W2_0 = (const float*)d_in[4];
    const float* W1_1 = (const float*)d_in[5];
    const float* W2_1 = (const float*)d_in[6];
    float* out = (float*)d_out;

    int n_nodes = in_sizes[0] / DIM;
    int n_edges = in_sizes[2];

    // ---- workspace carve-up (16B-aligned slices) ----
    char* p = (char*)d_ws;
    auto carve = [&](size_t bytes) {
        char* r = p;
        p += (bytes + 15) & ~(size_t)15;
        return r;
    };
    int*    cnt    = (int*)carve((size_t)n_nodes * sizeof(int));
    int*    offs   = (int*)carve(((size_t)n_nodes + 1) * sizeof(int));
    int*    cursor = (int*)carve((size_t)n_nodes * sizeof(int));
    float2* se     = (float2*)carve((size_t)n_edges * sizeof(float2));
    float*  agg    = (float*)carve((size_t)n_nodes * DIM * sizeof(float));

    int eb = (n_edges + 255) / 256;
    int gb = (n_nodes * DIM + 255) / 256;   // wave-per-node: 64 threads/node
    int mb = (n_nodes + 255) / 256;

    // ---- build dst-CSR (shared by both layers) ----
    hipMemsetAsync(cnt, 0, (size_t)n_nodes * sizeof(int), stream);
    hist_k<<<eb, 256, 0, stream>>>(ei, cnt, n_edges);
    scan_k<<<1, SCAN_T, 0, stream>>>(cnt, offs, cursor, n_nodes);
    reorder_k<<<eb, 256, 0, stream>>>(ei, ew, cursor, se, n_edges);

    // ---- layer 1 ----
    gather_k<<<gb, 256, 0, stream>>>(x, se, offs, agg, n_nodes);
    mlp_k<<<mb, 256, 0, stream>>>(agg, W1_0, W2_0, out, n_nodes, 0);

    // ---- layer 2 (x1 lives in d_out) ----
    gather_k<<<gb, 256, 0, stream>>>(out, se, offs, agg, n_nodes);
    mlp_k<<<mb, 256, 0, stream>>>(agg, W1_1, W2_1, out, n_nodes, 1);
}

// Round 3
// 324.476 us; speedup vs baseline: 4.6946x; 1.3827x over previous
//
#include <hip/hip_runtime.h>

// WeightedGIN 2-layer + L2-normalize. N=50000, E=800000, D=64.
// dst-CSR built per call (hist + hierarchical scan + reorder), then atomic-free
// wave-per-node gather for both layers, thread-per-node MLP with LDS weights.

#define DIM 64
#define SB 256   // scan block size

// ---- Pass 1: histogram of dst ----
__global__ __launch_bounds__(256) void hist_k(const int* __restrict__ ei,
                                              int* __restrict__ cnt, int n_edges) {
    int e = blockIdx.x * blockDim.x + threadIdx.x;
    if (e < n_edges) atomicAdd(&cnt[ei[n_edges + e]], 1);
}

// ---- Scan stage 1: per-block sums of cnt ----
__global__ __launch_bounds__(SB) void scan1_k(const int* __restrict__ cnt,
                                              int* __restrict__ bsum, int n) {
    __shared__ int red[SB];
    int i = blockIdx.x * SB + threadIdx.x;
    red[threadIdx.x] = (i < n) ? cnt[i] : 0;
    __syncthreads();
    for (int off = SB / 2; off > 0; off >>= 1) {
        if (threadIdx.x < off) red[threadIdx.x] += red[threadIdx.x + off];
        __syncthreads();
    }
    if (threadIdx.x == 0) bsum[blockIdx.x] = red[0];
}

// ---- Scan stage 2: exclusive scan of block sums (nb <= 1024) ----
__global__ __launch_bounds__(1024) void scan2_k(int* __restrict__ bsum, int nb) {
    __shared__ int sc[1024];
    int t = threadIdx.x;
    int v = (t < nb) ? bsum[t] : 0;
    sc[t] = v;
    __syncthreads();
    for (int off = 1; off < 1024; off <<= 1) {
        int u = (t >= off) ? sc[t - off] : 0;
        __syncthreads();
        sc[t] += u;
        __syncthreads();
    }
    if (t < nb) bsum[t] = sc[t] - v;   // exclusive prefix
}

// ---- Scan stage 3: block-local exclusive scan + block offset -> offs, cursor ----
__global__ __launch_bounds__(SB) void scan3_k(const int* __restrict__ cnt,
                                              const int* __restrict__ bsum,
                                              int* __restrict__ offs,
                                              int* __restrict__ cursor, int n) {
    __shared__ int sc[SB];
    int t = threadIdx.x;
    int i = blockIdx.x * SB + t;
    int v = (i < n) ? cnt[i] : 0;
    sc[t] = v;
    __syncthreads();
    for (int off = 1; off < SB; off <<= 1) {
        int u = (t >= off) ? sc[t - off] : 0;
        __syncthreads();
        sc[t] += u;
        __syncthreads();
    }
    int excl = sc[t] - v + bsum[blockIdx.x];
    if (i < n) { offs[i] = excl; cursor[i] = excl; }
    if (i == n - 1) offs[n] = excl + v;
}

// ---- Pass 3: scatter edges into dst-sorted payload (src_bits, w) ----
__global__ __launch_bounds__(256) void reorder_k(const int* __restrict__ ei,
                                                 const float* __restrict__ ew,
                                                 int* __restrict__ cursor,
                                                 float2* __restrict__ se, int n_edges) {
    int e = blockIdx.x * blockDim.x + threadIdx.x;
    if (e >= n_edges) return;
    int s = ei[e];
    int d = ei[n_edges + e];
    int pos = atomicAdd(&cursor[d], 1);
    se[pos] = make_float2(__int_as_float(s), ew[e]);
}

// ---- Per layer: wave-per-node gather-accumulate (atomic-free) ----
// Lane i owns feature i. 4-edge unroll, float4 payload loads (2 edges / 16B).
__global__ __launch_bounds__(256) void gather_k(const float* __restrict__ x,
                                                const float4* __restrict__ se4,
                                                const int* __restrict__ offs,
                                                float* __restrict__ agg, int n_nodes) {
    int w = (blockIdx.x * blockDim.x + threadIdx.x) >> 6;
    int lane = threadIdx.x & 63;
    if (w >= n_nodes) return;
    int beg = offs[w], end = offs[w + 1];
    const float2* se2 = reinterpret_cast<const float2*>(se4);
    float acc0 = 0.f, acc1 = 0.f, acc2 = 0.f, acc3 = 0.f;
    int e = beg;
    if ((e & 1) && e < end) {                       // align to float4 boundary
        float2 p = se2[e];
        acc0 = fmaf(p.y, x[(size_t)__float_as_int(p.x) * DIM + lane], acc0);
        ++e;
    }
    for (; e + 3 < end; e += 4) {                   // 4 edges / iter, 2x float4
        float4 q0 = se4[e >> 1];
        float4 q1 = se4[(e >> 1) + 1];
        acc0 = fmaf(q0.y, x[(size_t)__float_as_int(q0.x) * DIM + lane], acc0);
        acc1 = fmaf(q0.w, x[(size_t)__float_as_int(q0.z) * DIM + lane], acc1);
        acc2 = fmaf(q1.y, x[(size_t)__float_as_int(q1.x) * DIM + lane], acc2);
        acc3 = fmaf(q1.w, x[(size_t)__float_as_int(q1.z) * DIM + lane], acc3);
    }
    for (; e < end; ++e) {
        float2 p = se2[e];
        acc0 = fmaf(p.y, x[(size_t)__float_as_int(p.x) * DIM + lane], acc0);
    }
    agg[(size_t)w * DIM + lane] = (acc0 + acc1) + (acc2 + acc3);
}

// ---- MLP: out = relu(agg @ W1.T) @ W2.T, optional row L2-normalize ----
__global__ __launch_bounds__(256) void mlp_k(const float* __restrict__ agg,
                                             const float* __restrict__ W1,
                                             const float* __restrict__ W2,
                                             float* __restrict__ out,
                                             int n_nodes, int do_norm) {
    __shared__ float4 sW1[DIM * (DIM / 4)];    // [j][k4]
    __shared__ float4 sW2T[DIM * (DIM / 4)];   // [j][j2_4] = W2[j2][j] transposed
    for (int i = threadIdx.x; i < DIM * (DIM / 4); i += blockDim.x)
        sW1[i] = reinterpret_cast<const float4*>(W1)[i];
    for (int i = threadIdx.x; i < DIM * DIM; i += blockDim.x) {
        int j2 = i >> 6, j = i & 63;
        reinterpret_cast<float*>(sW2T)[j * DIM + j2] = W2[i];
    }
    __syncthreads();

    int node = blockIdx.x * blockDim.x + threadIdx.x;
    if (node >= n_nodes) return;

    float4 a[DIM / 4];
#pragma unroll
    for (int k4 = 0; k4 < DIM / 4; ++k4)
        a[k4] = reinterpret_cast<const float4*>(agg + (size_t)node * DIM)[k4];

    float4 o[DIM / 4];
#pragma unroll
    for (int j4 = 0; j4 < DIM / 4; ++j4) o[j4] = make_float4(0.f, 0.f, 0.f, 0.f);

    for (int j = 0; j < DIM; ++j) {
        float h = 0.f;
#pragma unroll
        for (int k4 = 0; k4 < DIM / 4; ++k4) {
            float4 wv = sW1[j * (DIM / 4) + k4];
            h = fmaf(a[k4].x, wv.x, h);
            h = fmaf(a[k4].y, wv.y, h);
            h = fmaf(a[k4].z, wv.z, h);
            h = fmaf(a[k4].w, wv.w, h);
        }
        h = fmaxf(h, 0.f);
#pragma unroll
        for (int j4 = 0; j4 < DIM / 4; ++j4) {
            float4 wv = sW2T[j * (DIM / 4) + j4];
            o[j4].x = fmaf(h, wv.x, o[j4].x);
            o[j4].y = fmaf(h, wv.y, o[j4].y);
            o[j4].z = fmaf(h, wv.z, o[j4].z);
            o[j4].w = fmaf(h, wv.w, o[j4].w);
        }
    }

    float scale = 1.f;
    if (do_norm) {
        float ss = 0.f;
#pragma unroll
        for (int j4 = 0; j4 < DIM / 4; ++j4) {
            ss = fmaf(o[j4].x, o[j4].x, ss);
            ss = fmaf(o[j4].y, o[j4].y, ss);
            ss = fmaf(o[j4].z, o[j4].z, ss);
            ss = fmaf(o[j4].w, o[j4].w, ss);
        }
        scale = 1.f / fmaxf(sqrtf(ss), 1e-12f);
    }

#pragma unroll
    for (int j4 = 0; j4 < DIM / 4; ++j4) {
        float4 v = o[j4];
        v.x *= scale; v.y *= scale; v.z *= scale; v.w *= scale;
        reinterpret_cast<float4*>(out + (size_t)node * DIM)[j4] = v;
    }
}

extern "C" void kernel_launch(void* const* d_in, const int* in_sizes, int n_in,
                              void* d_out, int out_size, void* d_ws, size_t ws_size,
                              hipStream_t stream) {
    const float* x    = (const float*)d_in[0];
    const int*   ei   = (const int*)d_in[1];     // [2,E]: src row then dst row
    const float* ew   = (const float*)d_in[2];
    const float* W1_0 = (const float*)d_in[3];
    const float* W2_0 = (const float*)d_in[4];
    const float* W1_1 = (const float*)d_in[5];
    const float* W2_1 = (const float*)d_in[6];
    float* out = (float*)d_out;

    int n_nodes = in_sizes[0] / DIM;
    int n_edges = in_sizes[2];

    // ---- workspace carve-up (16B-aligned slices) ----
    char* p = (char*)d_ws;
    auto carve = [&](size_t bytes) {
        char* r = p;
        p += (bytes + 15) & ~(size_t)15;
        return r;
    };
    int nb = (n_nodes + SB - 1) / SB;                // scan blocks (196)
    int*    cnt    = (int*)carve((size_t)n_nodes * sizeof(int));
    int*    offs   = (int*)carve(((size_t)n_nodes + 1) * sizeof(int));
    int*    cursor = (int*)carve((size_t)n_nodes * sizeof(int));
    int*    bsum   = (int*)carve((size_t)nb * sizeof(int));
    float2* se     = (float2*)carve((size_t)n_edges * sizeof(float2));
    float*  agg    = (float*)carve((size_t)n_nodes * DIM * sizeof(float));

    int eb = (n_edges + 255) / 256;
    int gb = (n_nodes * DIM + 255) / 256;   // wave-per-node: 64 threads/node
    int mb = (n_nodes + 255) / 256;

    // ---- build dst-CSR (shared by both layers) ----
    hipMemsetAsync(cnt, 0, (size_t)n_nodes * sizeof(int), stream);
    hist_k<<<eb, 256, 0, stream>>>(ei, cnt, n_edges);
    scan1_k<<<nb, SB, 0, stream>>>(cnt, bsum, n_nodes);
    scan2_k<<<1, 1024, 0, stream>>>(bsum, nb);
    scan3_k<<<nb, SB, 0, stream>>>(cnt, bsum, offs, cursor, n_nodes);
    reorder_k<<<eb, 256, 0, stream>>>(ei, ew, cursor, se, n_edges);

    // ---- layer 1 ----
    gather_k<<<gb, 256, 0, stream>>>(x, (const float4*)se, offs, agg, n_nodes);
    mlp_k<<<mb, 256, 0, stream>>>(agg, W1_0, W2_0, out, n_nodes, 0);

    // ---- layer 2 (x1 lives in d_out) ----
    gather_k<<<gb, 256, 0, stream>>>(out, (const float4*)se, offs, agg, n_nodes);
    mlp_k<<<mb, 256, 0, stream>>>(agg, W1_1, W2_1, out, n_nodes, 1);
}

// Round 5
// 316.538 us; speedup vs baseline: 4.8123x; 1.0251x over previous
//
#include <hip/hip_runtime.h>

// WeightedGIN 2-layer + L2-normalize. N=50000, E=800000, D=64.
// dst-CSR built per call (hist + 2-stage scan + reorder), then atomic-free
// 16-lane-per-node gather (float4 rows) for both layers, thread-per-node MLP.

#define DIM 64
#define SB 256   // scan block size

// ---- Pass 1: histogram of dst ----
__global__ __launch_bounds__(256) void hist_k(const int* __restrict__ ei,
                                              int* __restrict__ cnt, int n_edges) {
    int e = blockIdx.x * blockDim.x + threadIdx.x;
    if (e < n_edges) atomicAdd(&cnt[ei[n_edges + e]], 1);
}

// ---- Scan stage 1: per-block sums of cnt ----
__global__ __launch_bounds__(SB) void scan1_k(const int* __restrict__ cnt,
                                              int* __restrict__ bsum, int n) {
    __shared__ int red[SB];
    int i = blockIdx.x * SB + threadIdx.x;
    red[threadIdx.x] = (i < n) ? cnt[i] : 0;
    __syncthreads();
    for (int off = SB / 2; off > 0; off >>= 1) {
        if (threadIdx.x < off) red[threadIdx.x] += red[threadIdx.x + off];
        __syncthreads();
    }
    if (threadIdx.x == 0) bsum[blockIdx.x] = red[0];
}

// ---- Scan stage 2: each block re-scans bsum (nb<=256) + local scan -> offs, cursor ----
__global__ __launch_bounds__(SB) void scan3_k(const int* __restrict__ cnt,
                                              const int* __restrict__ bsum,
                                              int* __restrict__ offs,
                                              int* __restrict__ cursor, int n, int nb) {
    __shared__ int sb[SB];
    __shared__ int sc[SB];
    int t = threadIdx.x;
    // inclusive scan of block sums (nb <= 256)
    int bv = (t < nb) ? bsum[t] : 0;
    sb[t] = bv;
    __syncthreads();
    for (int off = 1; off < SB; off <<= 1) {
        int u = (t >= off) ? sb[t - off] : 0;
        __syncthreads();
        sb[t] += u;
        __syncthreads();
    }
    int block_off = (blockIdx.x == 0) ? 0 : sb[blockIdx.x - 1];
    __syncthreads();
    // local scan of this block's cnt chunk
    int i = blockIdx.x * SB + t;
    int v = (i < n) ? cnt[i] : 0;
    sc[t] = v;
    __syncthreads();
    for (int off = 1; off < SB; off <<= 1) {
        int u = (t >= off) ? sc[t - off] : 0;
        __syncthreads();
        sc[t] += u;
        __syncthreads();
    }
    int excl = sc[t] - v + block_off;
    if (i < n) { offs[i] = excl; cursor[i] = excl; }
    if (i == n - 1) offs[n] = excl + v;
}

// ---- Pass 3: scatter edges into dst-sorted payload (src_bits, w) ----
__global__ __launch_bounds__(256) void reorder_k(const int* __restrict__ ei,
                                                 const float* __restrict__ ew,
                                                 int* __restrict__ cursor,
                                                 float2* __restrict__ se, int n_edges) {
    int e = blockIdx.x * blockDim.x + threadIdx.x;
    if (e >= n_edges) return;
    int s = ei[e];
    int d = ei[n_edges + e];
    int pos = atomicAdd(&cursor[d], 1);
    se[pos] = make_float2(__int_as_float(s), ew[e]);
}

// ---- Per layer: 16-lane-per-node gather (atomic-free) ----
// Group of 16 lanes owns one node; lane li holds float4 chunk li of the 64-f row.
// One global_load_dwordx4 serves 4 edges (4 groups/wave), 4-edge unroll for MLP.
__global__ __launch_bounds__(256) void gather_k(const float4* __restrict__ x4,
                                                const float4* __restrict__ se4,
                                                const int* __restrict__ offs,
                                                float4* __restrict__ agg4, int n_nodes) {
    int t = blockIdx.x * blockDim.x + threadIdx.x;
    int node = t >> 4;
    int li = t & 15;
    if (node >= n_nodes) return;
    int beg = offs[node], end = offs[node + 1];
    const float2* se2 = reinterpret_cast<const float2*>(se4);

    float4 a0 = make_float4(0.f, 0.f, 0.f, 0.f);
    float4 a1 = make_float4(0.f, 0.f, 0.f, 0.f);
    float4 a2 = make_float4(0.f, 0.f, 0.f, 0.f);
    float4 a3 = make_float4(0.f, 0.f, 0.f, 0.f);

    int e = beg;
    if ((e & 1) && e < end) {                     // align to float4 payload boundary
        float2 p = se2[e];
        float4 v = x4[(size_t)__float_as_int(p.x) * 16 + li];
        a0.x = fmaf(p.y, v.x, a0.x); a0.y = fmaf(p.y, v.y, a0.y);
        a0.z = fmaf(p.y, v.z, a0.z); a0.w = fmaf(p.y, v.w, a0.w);
        ++e;
    }
    for (; e + 3 < end; e += 4) {                 // 4 edges: 2 payload f4 + 4 row f4 loads
        float4 qa = se4[e >> 1];
        float4 qb = se4[(e >> 1) + 1];
        float4 v0 = x4[(size_t)__float_as_int(qa.x) * 16 + li];
        float4 v1 = x4[(size_t)__float_as_int(qa.z) * 16 + li];
        float4 v2 = x4[(size_t)__float_as_int(qb.x) * 16 + li];
        float4 v3 = x4[(size_t)__float_as_int(qb.z) * 16 + li];
        a0.x = fmaf(qa.y, v0.x, a0.x); a0.y = fmaf(qa.y, v0.y, a0.y);
        a0.z = fmaf(qa.y, v0.z, a0.z); a0.w = fmaf(qa.y, v0.w, a0.w);
        a1.x = fmaf(qa.w, v1.x, a1.x); a1.y = fmaf(qa.w, v1.y, a1.y);
        a1.z = fmaf(qa.w, v1.z, a1.z); a1.w = fmaf(qa.w, v1.w, a1.w);
        a2.x = fmaf(qb.y, v2.x, a2.x); a2.y = fmaf(qb.y, v2.y, a2.y);
        a2.z = fmaf(qb.y, v2.z, a2.z); a2.w = fmaf(qb.y, v2.w, a2.w);
        a3.x = fmaf(qb.w, v3.x, a3.x); a3.y = fmaf(qb.w, v3.y, a3.y);
        a3.z = fmaf(qb.w, v3.z, a3.z); a3.w = fmaf(qb.w, v3.w, a3.w);
    }
    if (e + 1 < end) {                            // 2-edge chunk
        float4 qa = se4[e >> 1];
        float4 v0 = x4[(size_t)__float_as_int(qa.x) * 16 + li];
        float4 v1 = x4[(size_t)__float_as_int(qa.z) * 16 + li];
        a0.x = fmaf(qa.y, v0.x, a0.x); a0.y = fmaf(qa.y, v0.y, a0.y);
        a0.z = fmaf(qa.y, v0.z, a0.z); a0.w = fmaf(qa.y, v0.w, a0.w);
        a1.x = fmaf(qa.w, v1.x, a1.x); a1.y = fmaf(qa.w, v1.y, a1.y);
        a1.z = fmaf(qa.w, v1.z, a1.z); a1.w = fmaf(qa.w, v1.w, a1.w);
        e += 2;
    }
    if (e < end) {                                // last odd edge
        float2 p = se2[e];
        float4 v = x4[(size_t)__float_as_int(p.x) * 16 + li];
        a0.x = fmaf(p.y, v.x, a0.x); a0.y = fmaf(p.y, v.y, a0.y);
        a0.z = fmaf(p.y, v.z, a0.z); a0.w = fmaf(p.y, v.w, a0.w);
    }
    float4 r;
    r.x = (a0.x + a1.x) + (a2.x + a3.x);
    r.y = (a0.y + a1.y) + (a2.y + a3.y);
    r.z = (a0.z + a1.z) + (a2.z + a3.z);
    r.w = (a0.w + a1.w) + (a2.w + a3.w);
    agg4[(size_t)node * 16 + li] = r;
}

// ---- MLP: out = relu(agg @ W1.T) @ W2.T, optional row L2-normalize ----
// sW2T stored XOR-swizzled at float4 granularity: slot(j, j4) = j*16 + (j4 ^ (j&15)).
__global__ __launch_bounds__(256) void mlp_k(const float* __restrict__ agg,
                                             const float* __restrict__ W1,
                                             const float* __restrict__ W2,
                                             float* __restrict__ out,
                                             int n_nodes, int do_norm) {
    __shared__ float4 sW1[DIM * (DIM / 4)];     // [j][k4]
    __shared__ float4 sW2T4[DIM * (DIM / 4)];   // swizzled: logical [j][j2] = W2[j2][j]
    for (int i = threadIdx.x; i < DIM * (DIM / 4); i += blockDim.x)
        sW1[i] = reinterpret_cast<const float4*>(W1)[i];
    for (int i = threadIdx.x; i < DIM * DIM; i += blockDim.x) {
        int j2 = i >> 6, j = i & 63;
        int slot = j * 16 + ((j2 >> 2) ^ (j & 15));
        reinterpret_cast<float*>(sW2T4)[slot * 4 + (j2 & 3)] = W2[i];
    }
    __syncthreads();

    int node = blockIdx.x * blockDim.x + threadIdx.x;
    if (node >= n_nodes) return;

    float4 a[DIM / 4];
#pragma unroll
    for (int k4 = 0; k4 < DIM / 4; ++k4)
        a[k4] = reinterpret_cast<const float4*>(agg + (size_t)node * DIM)[k4];

    float4 o[DIM / 4];
#pragma unroll
    for (int j4 = 0; j4 < DIM / 4; ++j4) o[j4] = make_float4(0.f, 0.f, 0.f, 0.f);

    for (int j = 0; j < DIM; ++j) {
        float h = 0.f;
#pragma unroll
        for (int k4 = 0; k4 < DIM / 4; ++k4) {
            float4 wv = sW1[j * (DIM / 4) + k4];
            h = fmaf(a[k4].x, wv.x, h);
            h = fmaf(a[k4].y, wv.y, h);
            h = fmaf(a[k4].z, wv.z, h);
            h = fmaf(a[k4].w, wv.w, h);
        }
        h = fmaxf(h, 0.f);
#pragma unroll
        for (int j4 = 0; j4 < DIM / 4; ++j4) {
            float4 wv = sW2T4[j * 16 + (j4 ^ (j & 15))];
            o[j4].x = fmaf(h, wv.x, o[j4].x);
            o[j4].y = fmaf(h, wv.y, o[j4].y);
            o[j4].z = fmaf(h, wv.z, o[j4].z);
            o[j4].w = fmaf(h, wv.w, o[j4].w);
        }
    }

    float scale = 1.f;
    if (do_norm) {
        float ss = 0.f;
#pragma unroll
        for (int j4 = 0; j4 < DIM / 4; ++j4) {
            ss = fmaf(o[j4].x, o[j4].x, ss);
            ss = fmaf(o[j4].y, o[j4].y, ss);
            ss = fmaf(o[j4].z, o[j4].z, ss);
            ss = fmaf(o[j4].w, o[j4].w, ss);
        }
        scale = 1.f / fmaxf(sqrtf(ss), 1e-12f);
    }

#pragma unroll
    for (int j4 = 0; j4 < DIM / 4; ++j4) {
        float4 v = o[j4];
        v.x *= scale; v.y *= scale; v.z *= scale; v.w *= scale;
        reinterpret_cast<float4*>(out + (size_t)node * DIM)[j4] = v;
    }
}

extern "C" void kernel_launch(void* const* d_in, const int* in_sizes, int n_in,
                              void* d_out, int out_size, void* d_ws, size_t ws_size,
                              hipStream_t stream) {
    const float* x    = (const float*)d_in[0];
    const int*   ei   = (const int*)d_in[1];     // [2,E]: src row then dst row
    const float* ew   = (const float*)d_in[2];
    const float* W1_0 = (const float*)d_in[3];
    const float* W2_0 = (const float*)d_in[4];
    const float* W1_1 = (const float*)d_in[5];
    const float* W2_1 = (const float*)d_in[6];
    float* out = (float*)d_out;

    int n_nodes = in_sizes[0] / DIM;
    int n_edges = in_sizes[2];

    // ---- workspace carve-up (16B-aligned slices) ----
    char* p = (char*)d_ws;
    auto carve = [&](size_t bytes) {
        char* r = p;
        p += (bytes + 15) & ~(size_t)15;
        return r;
    };
    int nb = (n_nodes + SB - 1) / SB;                // 196 scan blocks (<=256)
    int*    cnt    = (int*)carve((size_t)n_nodes * sizeof(int));
    int*    offs   = (int*)carve(((size_t)n_nodes + 1) * sizeof(int));
    int*    cursor = (int*)carve((size_t)n_nodes * sizeof(int));
    int*    bsum   = (int*)carve((size_t)nb * sizeof(int));
    float2* se     = (float2*)carve((size_t)n_edges * sizeof(float2));
    float*  agg    = (float*)carve((size_t)n_nodes * DIM * sizeof(float));

    int eb = (n_edges + 255) / 256;
    int gb = (n_nodes * 16 + 255) / 256;    // 16 lanes per node
    int mb = (n_nodes + 255) / 256;

    // ---- build dst-CSR (shared by both layers) ----
    hipMemsetAsync(cnt, 0, (size_t)n_nodes * sizeof(int), stream);
    hist_k<<<eb, 256, 0, stream>>>(ei, cnt, n_edges);
    scan1_k<<<nb, SB, 0, stream>>>(cnt, bsum, n_nodes);
    scan3_k<<<nb, SB, 0, stream>>>(cnt, bsum, offs, cursor, n_nodes, nb);
    reorder_k<<<eb, 256, 0, stream>>>(ei, ew, cursor, se, n_edges);

    // ---- layer 1 ----
    gather_k<<<gb, 256, 0, stream>>>((const float4*)x, (const float4*)se, offs,
                                     (float4*)agg, n_nodes);
    mlp_k<<<mb, 256, 0, stream>>>(agg, W1_0, W2_0, out, n_nodes, 0);

    // ---- layer 2 (x1 lives in d_out) ----
    gather_k<<<gb, 256, 0, stream>>>((const float4*)out, (const float4*)se, offs,
                                     (float4*)agg, n_nodes);
    mlp_k<<<mb, 256, 0, stream>>>(agg, W1_1, W2_1, out, n_nodes, 1);
}